// Round 1
// baseline (433.961 us; speedup 1.0000x reference)
//
#include <hip/hip_runtime.h>
#include <stdint.h>

typedef short s16x8 __attribute__((ext_vector_type(8)));
typedef float f32x4 __attribute__((ext_vector_type(4)));

#define NPIX 65536
#define FEAT 224
#define PEND 6
#define HID  256

// fp32 -> bf16 round-to-nearest-even
__device__ __forceinline__ unsigned short f2bf(float x) {
  unsigned u = __float_as_uint(x);
  return (unsigned short)((u + 0x7FFFu + ((u >> 16) & 1u)) >> 16);
}
// order-preserving float<->uint for atomicMax
__device__ __forceinline__ unsigned fenc(float x) {
  unsigned u = __float_as_uint(x);
  return (u & 0x80000000u) ? ~u : (u | 0x80000000u);
}
__device__ __forceinline__ float fdec(unsigned u) {
  return __uint_as_float((u & 0x80000000u) ? (u & 0x7FFFFFFFu) : ~u);
}
__device__ __forceinline__ void glds16(const void* g, void* l) {
  __builtin_amdgcn_global_load_lds(
      (const __attribute__((address_space(1))) unsigned int*)g,
      (__attribute__((address_space(3))) unsigned int*)l, 16, 0, 0);
}

// ---- converts ----
__global__ void cvtY(const float* __restrict__ Y, unsigned short* __restrict__ Yb) {
  long i = ((long)blockIdx.x * 256 + threadIdx.x) * 4;
  float4 v = *(const float4*)(Y + i);
  ushort4 o;
  o.x = f2bf(v.x); o.y = f2bf(v.y); o.z = f2bf(v.z); o.w = f2bf(v.w);
  *(ushort4*)(Yb + i) = o;
}

// W:[K][N] fp32 -> Wt:[NpadRows][K] bf16 (rows >= N zero)
__global__ void cvtWt(const float* __restrict__ W, unsigned short* __restrict__ Wt,
                      int K, int N, int NpadRows) {
  int i = blockIdx.x * 256 + threadIdx.x;
  if (i >= NpadRows * K) return;
  int n = i / K, k = i - n * K;
  unsigned short v = 0;
  if (n < N) v = f2bf(W[(long)k * N + n]);
  Wt[i] = v;
}

// ---- argmax class + counts ----
__global__ void clsk(const float* __restrict__ ab, int* __restrict__ cls,
                     int* __restrict__ counts) {
  int n = blockIdx.x * 256 + threadIdx.x;
  const float* a = ab + (long)n * PEND;
  float best = a[0]; int bi = 0;
#pragma unroll
  for (int p = 1; p < PEND; p++) { float v = a[p]; if (v > best) { best = v; bi = p; } }
  cls[n] = bi;
#pragma unroll
  for (int p = 0; p < PEND; p++) {
    unsigned long long m = __ballot(bi == p);
    if ((threadIdx.x & 63) == 0) {
      int c = __popcll(m);
      if (c) atomicAdd(&counts[p], c);
    }
  }
}

// ---- bf16 MFMA GEMM, A:[M][K] bf16 row-major, Bt:[Ncols][K] bf16 (B transposed) ----
template <int RELU, int OUTBF>
__global__ __launch_bounds__(256)
void gemm_bt(const unsigned short* __restrict__ A, const unsigned short* __restrict__ Bt,
             const float* __restrict__ bias, void* __restrict__ Cout,
             int K, int Nout, int Nreal) {
  constexpr int BM = 128, BN = 128, BK = 32;
  __shared__ __align__(16) unsigned short As[BM * BK];
  __shared__ __align__(16) unsigned short Bs[BN * BK];
  const int tid = threadIdx.x;
  const int wid = tid >> 6;
  const int lane = tid & 63;
  const int wm = wid >> 1, wn = wid & 1;
  const long row0 = (long)blockIdx.x * BM;
  const int n0 = blockIdx.y * BN;

  // staging: wave wid covers 32 tile-rows; lane -> (row = lane/4, 16B chunk = lane%4)
  const int ldr = lane >> 2;
  const int ldk = (lane & 3) * 8;
  const unsigned short* Ap = A + (row0 + wid * 32 + ldr) * (long)K + ldk;
  const unsigned short* Bp = Bt + (long)(n0 + wid * 32 + ldr) * K + ldk;
  unsigned short* AsW = As + (wid * 32) * BK;
  unsigned short* BsW = Bs + (wid * 32) * BK;

  f32x4 acc[4][4];
#pragma unroll
  for (int i = 0; i < 4; i++)
#pragma unroll
    for (int j = 0; j < 4; j++) acc[i][j] = {0.f, 0.f, 0.f, 0.f};

  const int mrow = lane & 15;
  const int quad = lane >> 4;
  const unsigned short* Abase = As + (wm * 64 + mrow) * BK + quad * 8;
  const unsigned short* Bbase = Bs + (wn * 64 + mrow) * BK + quad * 8;

  for (int k0 = 0; k0 < K; k0 += BK) {
    glds16(Ap + k0, AsW);
    glds16(Ap + k0 + 16 * (long)K, AsW + 16 * BK);
    glds16(Bp + k0, BsW);
    glds16(Bp + k0 + 16 * (long)K, BsW + 16 * BK);
    __syncthreads();  // vmcnt(0) drain -> LDS valid
    s16x8 af[4], bfv[4];
#pragma unroll
    for (int i = 0; i < 4; i++) af[i] = *(const s16x8*)(Abase + i * 16 * BK);
#pragma unroll
    for (int j = 0; j < 4; j++) bfv[j] = *(const s16x8*)(Bbase + j * 16 * BK);
#pragma unroll
    for (int i = 0; i < 4; i++)
#pragma unroll
      for (int j = 0; j < 4; j++)
        acc[i][j] = __builtin_amdgcn_mfma_f32_16x16x32_bf16(af[i], bfv[j], acc[i][j], 0, 0, 0);
    __syncthreads();  // protect LDS before next stage
  }

  // epilogue: C/D layout col=lane&15, row=(lane>>4)*4+reg  [m89/m91-verified]
#pragma unroll
  for (int j = 0; j < 4; j++) {
    int col = n0 + wn * 64 + j * 16 + mrow;
    bool ok = col < Nreal;
    float bb = ok ? bias[col] : 0.f;
#pragma unroll
    for (int i = 0; i < 4; i++) {
      long r0 = row0 + wm * 64 + i * 16 + quad * 4;
#pragma unroll
      for (int r = 0; r < 4; r++) {
        float v = acc[i][j][r] + bb;
        if (RELU) v = fmaxf(v, 0.f);
        if (ok) {
          if (OUTBF)
            ((unsigned short*)Cout)[(size_t)(r0 + r) * Nout + col] = f2bf(v);
          else
            ((float*)Cout)[(size_t)(r0 + r) * Nout + col] = v;
        }
      }
    }
  }
}

// ---- pass1: per-(class,feature) max over pixels ----
__global__ void pass1(const float* __restrict__ logits, const int* __restrict__ cls,
                      unsigned* __restrict__ gmax) {
  int t = threadIdx.x;
  long n0 = (long)blockIdx.x * 256;
  if (t >= FEAT) return;
  float lm[PEND];
#pragma unroll
  for (int p = 0; p < PEND; p++) lm[p] = -3.4e38f;
  for (int r = 0; r < 256; r++) {
    long n = n0 + r;
    int c = cls[n];  // block-uniform
    float v = logits[n * FEAT + t];
#pragma unroll
    for (int p = 0; p < PEND; p++)
      if (p == c) lm[p] = fmaxf(lm[p], v);
  }
#pragma unroll
  for (int p = 0; p < PEND; p++) atomicMax(&gmax[p * FEAT + t], fenc(lm[p]));
}

// ---- pass2: per-(class,feature) sum(exp) and sum(exp*Y) ----
__global__ void pass2(const float* __restrict__ logits, const float* __restrict__ Y,
                      const int* __restrict__ cls, const unsigned* __restrict__ gmax,
                      float* __restrict__ gsum, float* __restrict__ gsumY) {
  int t = threadIdx.x;
  long n0 = (long)blockIdx.x * 256;
  if (t >= FEAT) return;
  float gm[PEND], s[PEND], sy[PEND];
#pragma unroll
  for (int p = 0; p < PEND; p++) {
    gm[p] = fdec(gmax[p * FEAT + t]);
    s[p] = 0.f; sy[p] = 0.f;
  }
  for (int r = 0; r < 256; r++) {
    long n = n0 + r;
    int c = cls[n];  // block-uniform
    float g = gm[0];
#pragma unroll
    for (int p = 1; p < PEND; p++) g = (c == p) ? gm[p] : g;
    float e = __expf(logits[n * FEAT + t] - g);
    float yv = Y[n * FEAT + t];
#pragma unroll
    for (int p = 0; p < PEND; p++) {
      s[p] += (c == p) ? e : 0.f;
      sy[p] += (c == p) ? e * yv : 0.f;
    }
  }
#pragma unroll
  for (int p = 0; p < PEND; p++) {
    atomicAdd(&gsum[p * FEAT + t], s[p]);
    atomicAdd(&gsumY[p * FEAT + t], sy[p]);
  }
}

// ---- build M and Y_hat = abundance @ M ----
__global__ void yhat(const float* __restrict__ ab, const float* __restrict__ gsum,
                     const float* __restrict__ gsumY, const int* __restrict__ counts,
                     float* __restrict__ out) {
  __shared__ float Ms[PEND * FEAT];
  __shared__ float aS[256 * PEND];
  int t = threadIdx.x;
  for (int i = t; i < PEND * FEAT; i += 256) {
    int p = i / FEAT;
    float m = 0.f;
    if (counts[p] > 0) m = gsumY[i] / gsum[i];
    Ms[i] = m;
  }
  long n0 = (long)blockIdx.x * 256;
  const float* abb = ab + n0 * PEND;
  for (int i = t; i < 256 * PEND; i += 256) aS[i] = abb[i];
  __syncthreads();
  if (t < FEAT) {
    for (int r = 0; r < 256; r++) {
      float acc = 0.f;
#pragma unroll
      for (int p = 0; p < PEND; p++) acc += aS[r * PEND + p] * Ms[p * FEAT + t];
      out[(n0 + r) * FEAT + t] = acc;
    }
  }
}

extern "C" void kernel_launch(void* const* d_in, const int* in_sizes, int n_in,
                              void* d_out, int out_size, void* d_ws, size_t ws_size,
                              hipStream_t stream) {
  const float* ab = (const float*)d_in[0];
  const float* Y  = (const float*)d_in[1];
  const float* W1 = (const float*)d_in[2];
  const float* b1 = (const float*)d_in[3];
  const float* W2 = (const float*)d_in[4];
  const float* b2 = (const float*)d_in[5];
  const float* W3 = (const float*)d_in[6];
  const float* b3 = (const float*)d_in[7];
  float* out = (float*)d_out;

  char* ws = (char*)d_ws;
  // layout (bytes); logits aliases dead Ybf+h1 region
  const size_t oYbf   = 0;                 // 65536*224*2 = 29,360,128
  const size_t oh1    = 29360128;          // 65536*256*2 = 33,554,432
  const size_t ologit = 0;                 // 65536*224*4 = 58,720,256 (alias)
  const size_t oh2    = 62914560;          // 33,554,432
  const size_t oW1t   = 96468992;          // 256*224*2 = 114,688
  const size_t oW2t   = 96583680;          // 256*256*2 = 131,072
  const size_t oW3t   = 96714752;          // 256*256*2 = 131,072 (rows>=224 zero)
  const size_t ocls   = 96845824;          // 65536*4  = 262,144
  const size_t osmall = 97107968;          // counts(32) + gmax(5376) + gsum(5376) + gsumY(5376)

  unsigned short* Ybf = (unsigned short*)(ws + oYbf);
  unsigned short* h1  = (unsigned short*)(ws + oh1);
  unsigned short* h2  = (unsigned short*)(ws + oh2);
  float*          lg  = (float*)(ws + ologit);
  unsigned short* W1t = (unsigned short*)(ws + oW1t);
  unsigned short* W2t = (unsigned short*)(ws + oW2t);
  unsigned short* W3t = (unsigned short*)(ws + oW3t);
  int*      cls    = (int*)(ws + ocls);
  int*      counts = (int*)(ws + osmall);
  unsigned* gmax   = (unsigned*)(ws + osmall + 32);
  float*    gsum   = (float*)(ws + osmall + 32 + 5376);
  float*    gsumY  = (float*)(ws + osmall + 32 + 10752);

  hipMemsetAsync(ws + osmall, 0, 32 + 3 * 5376, stream);

  cvtY<<<14336, 256, 0, stream>>>(Y, Ybf);
  cvtWt<<<224, 256, 0, stream>>>(W1, W1t, FEAT, HID, HID);   // [224][256] -> [256][224]
  cvtWt<<<256, 256, 0, stream>>>(W2, W2t, HID, HID, HID);    // [256][256] -> [256][256]
  cvtWt<<<256, 256, 0, stream>>>(W3, W3t, HID, FEAT, HID);   // [256][224] -> [256(pad)][256]
  clsk<<<256, 256, 0, stream>>>(ab, cls, counts);

  dim3 gg(512, 2, 1);
  gemm_bt<1, 1><<<gg, 256, 0, stream>>>(Ybf, W1t, b1, (void*)h1, FEAT, HID, HID);
  gemm_bt<1, 1><<<gg, 256, 0, stream>>>(h1, W2t, b2, (void*)h2, HID, HID, HID);
  gemm_bt<0, 0><<<gg, 256, 0, stream>>>(h2, W3t, b3, (void*)lg, HID, FEAT, FEAT);

  pass1<<<256, 256, 0, stream>>>(lg, cls, gmax);
  pass2<<<256, 256, 0, stream>>>(lg, Y, cls, gmax, gsum, gsumY);
  yhat<<<256, 256, 0, stream>>>(ab, gsum, gsumY, counts, out);
}